// Round 5
// baseline (19.910 us; speedup 1.0000x reference)
//
#include <hip/hip_runtime.h>
#include <math.h>

// ApproxCompressor, single-kernel, zero-synchronization, log2-domain version.
//
// Math: h[k] = (1-a)a^k FIR (K=16384) == one-pole IIR exactly in fp32
// (a^16384 <= e^-580 == 0 for a = sigmoid(N(0,1))).
//
// Carry-in for chunk c is recomputed redundantly from chunk c-1's raw data
// (dropped a^CL*carry term <= e^-73); threads whose decay weight flushes to
// zero skip the prev-chunk LOAD only. Round-4 post-mortem: the per-thread
// predicate must NOT wrap the shfl reduction / part[] publish — lane 0 is
// the most-attenuated thread and usually fails it, so the wave's sum was
// dropped (absmax 0.397). Reduction + publish are now unconditional.
//
// Knee gain computed entirely in log2 domain: with T2=T*log2e, W2=W*log2e,
// le2=log2(env+eps), the reference's ln-domain knee maps EXACTLY to
//   above: g2 = c*(le2-T2);  mid: g2 = c*(le2-T2+W2)^2/(4*W2);  gain = 2^g2
// (ln2 factors cancel), so v_log_f32/v_exp_f32 are used raw (<=1 ulp).

namespace {

constexpr int N_BATCH = 32;
constexpr int L_LEN   = 131072;
constexpr int NCHUNK  = 64;
constexpr int CL      = L_LEN / NCHUNK;   // 2048
constexpr int NTHR    = 256;
constexpr int SEG     = CL / NTHR;        // 8
constexpr int NWAVE   = NTHR / 64;        // 4
constexpr int NBLK    = NCHUNK * N_BATCH; // 2048
constexpr int NXCD    = 8;
constexpr float EPS_F = 1e-5f;
constexpr float LOG2E = 1.4426950408889634f;

__device__ __forceinline__ float fast_exp2(float x) {
#if __has_builtin(__builtin_amdgcn_exp2f)
    return __builtin_amdgcn_exp2f(x);
#else
    return exp2f(x);
#endif
}
__device__ __forceinline__ float fast_log2(float x) {
#if __has_builtin(__builtin_amdgcn_logf)
    return __builtin_amdgcn_logf(x);
#else
    return log2f(x);
#endif
}

// alpha = sigmoid(z), oma = 1-alpha, la2 = log2(alpha); numerically stable
__device__ __forceinline__ void batch_alpha(float z, float& alpha, float& oma, float& la2) {
    if (z >= 0.f) {
        float e = expf(-z);
        float d = 1.f + e;
        alpha = 1.f / d;
        oma   = e / d;
        la2   = -log1pf(e) * LOG2E;
    } else {
        float e = expf(z);
        float d = 1.f + e;
        alpha = e / d;
        oma   = 1.f / d;
        la2   = (z - log1pf(e)) * LOG2E;
    }
}

__global__ __launch_bounds__(NTHR, 4) void k_compress(
    const float* __restrict__ x,
    const float* __restrict__ z_alpha,
    const float* __restrict__ log_threshold,
    const float* __restrict__ log_ratio,
    const float* __restrict__ log_knee,
    float* __restrict__ out)
{
    // XCD-aware swizzle: consecutive chunks of one batch share an XCD's L2.
    const int bid  = blockIdx.x;
    const int work = (bid & (NXCD - 1)) * (NBLK / NXCD) + (bid >> 3);
    const int n    = work >> 6;
    const int c    = work & (NCHUNK - 1);
    const int t    = threadIdx.x;
    const int lane = t & 63;
    const int wv   = t >> 6;

    const size_t base = (size_t)n * 2 * L_LEN + (size_t)c * CL + (size_t)t * SEG;
    const float* x0 = x + base;
    const float* x1 = x0 + L_LEN;

    // ---- issue unconditional own-chunk loads FIRST ----
    float4 a0 = *reinterpret_cast<const float4*>(x0);
    float4 a1 = *reinterpret_cast<const float4*>(x0 + 4);
    float4 b0 = *reinterpret_cast<const float4*>(x1);
    float4 b1 = *reinterpret_cast<const float4*>(x1 + 4);

    float alpha, oma, la2;
    batch_alpha(z_alpha[n], alpha, oma, la2);
    const float h_oma = 0.5f * oma;

    __shared__ float part[NWAVE];
    __shared__ float wA[NWAVE], wB[NWAVE];

    // ---- carry from previous chunk (redundant recompute, no sync) ----
    // Per-thread predicate gates ONLY the loads+local work (exec-masked);
    // the reduction and publish run on all lanes unconditionally.
    const float wexp = (float)(SEG * (NTHR - 1 - t)) * la2;   // log2 of weight
    float v = 0.f;
    if (c > 0 && wexp > -126.f) {
        const float* p0 = x0 - CL;
        const float* p1 = p0 + L_LEN;
        float4 pa0 = *reinterpret_cast<const float4*>(p0);
        float4 pa1 = *reinterpret_cast<const float4*>(p0 + 4);
        float4 pb0 = *reinterpret_cast<const float4*>(p1);
        float4 pb1 = *reinterpret_cast<const float4*>(p1 + 4);
        float yl = 0.f;
        yl = fmaf(alpha, yl, h_oma * fmaf(pa0.x, pa0.x, pb0.x * pb0.x));
        yl = fmaf(alpha, yl, h_oma * fmaf(pa0.y, pa0.y, pb0.y * pb0.y));
        yl = fmaf(alpha, yl, h_oma * fmaf(pa0.z, pa0.z, pb0.z * pb0.z));
        yl = fmaf(alpha, yl, h_oma * fmaf(pa0.w, pa0.w, pb0.w * pb0.w));
        yl = fmaf(alpha, yl, h_oma * fmaf(pa1.x, pa1.x, pb1.x * pb1.x));
        yl = fmaf(alpha, yl, h_oma * fmaf(pa1.y, pa1.y, pb1.y * pb1.y));
        yl = fmaf(alpha, yl, h_oma * fmaf(pa1.z, pa1.z, pb1.z * pb1.z));
        yl = fmaf(alpha, yl, h_oma * fmaf(pa1.w, pa1.w, pb1.w * pb1.w));
        v = fast_exp2(wexp) * yl;
    }
    #pragma unroll
    for (int d = 32; d > 0; d >>= 1) v += __shfl_down(v, d);
    if (lane == 0) part[wv] = v;

    // ---- own chunk: energy + per-thread local scan ----
    float e[SEG];
    e[0] = fmaf(a0.x, a0.x, b0.x * b0.x);
    e[1] = fmaf(a0.y, a0.y, b0.y * b0.y);
    e[2] = fmaf(a0.z, a0.z, b0.z * b0.z);
    e[3] = fmaf(a0.w, a0.w, b0.w * b0.w);
    e[4] = fmaf(a1.x, a1.x, b1.x * b1.x);
    e[5] = fmaf(a1.y, a1.y, b1.y * b1.y);
    e[6] = fmaf(a1.z, a1.z, b1.z * b1.z);
    e[7] = fmaf(a1.w, a1.w, b1.w * b1.w);

    float f = 0.f;
    #pragma unroll
    for (int i = 0; i < SEG; ++i) f = fmaf(alpha, f, h_oma * e[i]);

    // in-wave Hillis-Steele inclusive scan of affine maps (A, b): y -> A*y + b
    float A = fast_exp2((float)SEG * la2);   // alpha^SEG
    float b = f;
    #pragma unroll
    for (int d = 1; d < 64; d <<= 1) {
        float Ap = __shfl_up(A, d);
        float bp = __shfl_up(b, d);
        if (lane >= d) {
            b = fmaf(A, bp, b);   // pre-update A!
            A *= Ap;
        }
    }
    if (lane == 63) { wA[wv] = A; wB[wv] = b; }

    __syncthreads();   // publishes part[] and wA/wB[]

    float carry = 0.f;
    if (c > 0) {
        #pragma unroll
        for (int k = 0; k < NWAVE; ++k) carry += part[k];
    }

    // exclusive prefix for this thread: waves 0..wv-1 composed, then lane-1
    float PA = 1.f, PB = 0.f;
    #pragma unroll
    for (int k = 0; k < NWAVE - 1; ++k) {
        if (k < wv) {
            PB = fmaf(wA[k], PB, wB[k]);
            PA *= wA[k];
        }
    }
    float EA = __shfl_up(A, 1);
    float EB = __shfl_up(b, 1);
    if (lane == 0) { EA = 1.f; EB = 0.f; }
    float y = fmaf(EA, fmaf(PA, carry, PB), EB);   // env entering this segment

    // ---- gain params, log2 domain ----
    const float T2    = (log_threshold[n] - 6.0f) * LOG2E;
    const float R     = 1.0f + expf(log_ratio[n]);
    const float cc    = 1.0f / R - 1.0f;
    const float W2    = expf(log_knee[n]) * LOG2E;
    const float i4W2  = 1.0f / (4.0f * W2);

    // ---- walk 2: exact envelope -> quadratic-knee gain (all log2/exp2) ----
    float gn[SEG];
    #pragma unroll
    for (int i = 0; i < SEG; ++i) {
        y = fmaf(alpha, y, h_oma * e[i]);
        float le2 = fast_log2(y + EPS_F);
        float g2;
        if (le2 >= T2 + W2) {
            g2 = cc * (le2 - T2);
        } else if (le2 < T2 - W2) {
            g2 = 0.f;
        } else {
            float u = le2 - T2 + W2;
            g2 = cc * u * u * i4W2;
        }
        gn[i] = fast_exp2(g2);
    }

    float* o0 = out + base;
    float* o1 = o0 + L_LEN;
    *reinterpret_cast<float4*>(o0)     = make_float4(gn[0]*a0.x, gn[1]*a0.y, gn[2]*a0.z, gn[3]*a0.w);
    *reinterpret_cast<float4*>(o0 + 4) = make_float4(gn[4]*a1.x, gn[5]*a1.y, gn[6]*a1.z, gn[7]*a1.w);
    *reinterpret_cast<float4*>(o1)     = make_float4(gn[0]*b0.x, gn[1]*b0.y, gn[2]*b0.z, gn[3]*b0.w);
    *reinterpret_cast<float4*>(o1 + 4) = make_float4(gn[4]*b1.x, gn[5]*b1.y, gn[6]*b1.z, gn[7]*b1.w);
}

} // namespace

extern "C" void kernel_launch(void* const* d_in, const int* in_sizes, int n_in,
                              void* d_out, int out_size, void* d_ws, size_t ws_size,
                              hipStream_t stream) {
    const float* x  = (const float*)d_in[0];   // input_signals (32, 2, 131072)
    const float* za = (const float*)d_in[1];   // z_alpha
    const float* lt = (const float*)d_in[2];   // log_threshold
    const float* lr = (const float*)d_in[3];   // log_ratio
    const float* lk = (const float*)d_in[4];   // log_knee
    float* out = (float*)d_out;

    k_compress<<<NBLK, NTHR, 0, stream>>>(x, za, lt, lr, lk, out);
}